// Round 15
// baseline (244.294 us; speedup 1.0000x reference)
//
#include <hip/hip_runtime.h>
#include <math.h>
#include <stdint.h>

#define NROWS 48000
#define KDIM 512
#define NE 320
#define GE 640
#define DDIM 384
#define ODIM 768
#define CB_OFF 36864000ul
#define SC_OFF 67584000ul
// 1-pass f16 GEMM: logits ~= Xh @ Wh^T + b. Dropped terms Xl*W + Xh*Wl give
// logit error sigma ~6.4e-3 (gap error sigma ~9e-3). Gumbel argmax is the
// only exactness-critical decision (cb/quantized); near-ties (gap < MARGIN
// = 13 sigma) are re-resolved in fp64 over the top-3 by the fixup kernel.
// Plain argmax feeds only code_perplexity (threshold 12.4; ~3e-3/flip).
#define MARGIN 0.12f
#define FLAGCAP 16384u

using f16x8 = __attribute__((ext_vector_type(8))) _Float16;
using f32x4 = __attribute__((ext_vector_type(4))) float;

#define GLD16(gp, lp)                                                          \
    __builtin_amdgcn_global_load_lds(                                          \
        (const __attribute__((address_space(1))) uint32_t*)(gp),               \
        (__attribute__((address_space(3))) uint32_t*)(lp), 16, 0, 0)

// ---------------- W f32 -> f16 hi (0.65 MB) --------------------------------
__global__ __launch_bounds__(256) void split_hi(const float* __restrict__ src,
                                                _Float16* __restrict__ hi,
                                                int n8)
{
    int i = blockIdx.x * 256 + threadIdx.x;
    if (i >= n8) return;
    float4 v0 = *((const float4*)src + 2 * (size_t)i);
    float4 v1 = *((const float4*)src + 2 * (size_t)i + 1);
    float x[8] = {v0.x, v0.y, v0.z, v0.w, v1.x, v1.y, v1.z, v1.w};
    f16x8 h;
    #pragma unroll
    for (int k = 0; k < 8; ++k) h[k] = (_Float16)x[k];
    *(f16x8*)(hi + (size_t)i * 8) = h;
}

// ---------------- Kernel A: logits ~= Xh @ Wh^T + b (1-pass MFMA) ---------
__global__ __launch_bounds__(256) void gemm_cvt(
    const float* __restrict__ X,
    const _Float16* __restrict__ Wh,
    const float* __restrict__ bvec, float* __restrict__ Lout)
{
    __shared__ _Float16 lds[8192];              // 16 KB: Ah|Bh, each [128][32]
    _Float16* Ahs = lds;
    _Float16* Bhs = lds + 4096;

    // bijective XCD swizzle (nwg=1875): q8=234, r8=3
    const int bid = blockIdx.x;
    const int q8 = 1875 / 8, r8 = 1875 % 8;
    const int xcd = bid & 7, wi = bid >> 3;
    const int wg = (xcd < r8 ? xcd * (q8 + 1) : r8 * (q8 + 1) + (xcd - r8) * q8) + wi;
    const int bm = wg / 5, bn = wg % 5;

    const int tid = threadIdx.x;
    const int wid = tid >> 6, lane = tid & 63;
    const int fr = lane & 15, fq = lane >> 4;
    const int wm = (wid >> 1) * 64, wn = (wid & 1) * 64;

    const float*     Ag  = X  + (size_t)(bm * 128) * KDIM;
    const _Float16*  Bhg = Wh + (size_t)(bn * 128) * KDIM;

    f32x4 acc[4][4];
    #pragma unroll
    for (int i = 0; i < 4; ++i)
        #pragma unroll
        for (int j = 0; j < 4; ++j)
            acc[i][j] = (f32x4){0.f, 0.f, 0.f, 0.f};

    for (int kk = 0; kk < 16; ++kk) {
        const int kh = kk * 32;
        // B staging via GLD16 (2 per lane)
        #pragma unroll
        for (int q = 0; q < 2; ++q) {
            const int c = wid * 2 + q;
            const int srow = lane >> 2, sc8 = (lane & 3) * 8;
            const size_t go = (size_t)(c * 16 + srow) * KDIM + kh + sc8;
            GLD16(Bhg + go, Bhs + c * 512);
        }
        // A staging: f32 -> f16 hi in-register -> LDS
        #pragma unroll
        for (int c = 0; c < 2; ++c) {
            const int idx8 = c * 256 + tid;
            const int row = idx8 >> 2, k8 = (idx8 & 3) * 8;
            const float4* xp = (const float4*)(Ag + (size_t)row * KDIM + kh + k8);
            float4 v0 = xp[0], v1 = xp[1];
            float xs[8] = {v0.x, v0.y, v0.z, v0.w, v1.x, v1.y, v1.z, v1.w};
            f16x8 h;
            #pragma unroll
            for (int q = 0; q < 8; ++q) h[q] = (_Float16)xs[q];
            *(f16x8*)&Ahs[row * 32 + k8] = h;
        }
        __syncthreads();

        f16x8 ah[4], bh[4];
        #pragma unroll
        for (int i = 0; i < 4; ++i) {
            const int ro = (wm + i * 16 + fr) * 32 + fq * 8;
            ah[i] = *(const f16x8*)&Ahs[ro];
            const int co = (wn + i * 16 + fr) * 32 + fq * 8;
            bh[i] = *(const f16x8*)&Bhs[co];
        }
        #pragma unroll
        for (int i = 0; i < 4; ++i)
            #pragma unroll
            for (int j = 0; j < 4; ++j)
                acc[i][j] = __builtin_amdgcn_mfma_f32_16x16x32_f16(ah[i], bh[j], acc[i][j], 0, 0, 0);
        __syncthreads();
    }

    // C/D layout: col = lane&15, row = (lane>>4)*4 + reg   [m89-verified]
    #pragma unroll
    for (int i = 0; i < 4; ++i) {
        #pragma unroll
        for (int r = 0; r < 4; ++r) {
            const int m = bm * 128 + wm + i * 16 + fq * 4 + r;
            float* orow = Lout + (size_t)m * GE + bn * 128 + wn;
            #pragma unroll
            for (int j = 0; j < 4; ++j) {
                const int n = bn * 128 + wn + j * 16 + fr;
                orow[j * 16 + fr] = acc[i][j][r] + bvec[n];
            }
        }
    }
}

// ---------------- helpers -------------------------------------------------
__device__ __forceinline__ bool better(float a, int ia, float b, int ib) {
    return (a > b) || (a == b && ia < ib);
}

// ---------------- Kernel B: epilogue (R14 shape, 2x grid for residency) ---
__global__ __launch_bounds__(256) void epilogue_kernel(
    const float* __restrict__ entries, const float* __restrict__ gumbel,
    float* __restrict__ out, float* __restrict__ gavgp,
    unsigned int* __restrict__ gcnt, unsigned int* __restrict__ nflag,
    uint2* __restrict__ flags)
{
    __shared__ float s_avgp[GE];
    __shared__ unsigned int s_cnt[GE];
    const int tid = threadIdx.x;
    for (int i = tid; i < GE; i += 256) { s_avgp[i] = 0.f; s_cnt[i] = 0u; }
    __syncthreads();

    const int wave = tid >> 6, lane = tid & 63;
    const int h = lane >> 5, il = lane & 31;

    float accp[10];
    #pragma unroll
    for (int i = 0; i < 10; ++i) accp[i] = 0.f;

    float* cb = out + CB_OFF;

    for (int rr = 0; rr < 4; ++rr) {
        const int n = blockIdx.x * 16 + wave * 4 + rr;
        float* Lrow = cb + (size_t)n * GE + h * NE;
        const float* Urow = gumbel + (size_t)(2 * n + h) * NE;

        // parallel load + trans loop: no cross-iteration deps
        float lg[10], zg[10];
        #pragma unroll
        for (int i = 0; i < 10; ++i) {
            const int e = il + 32 * i;
            lg[i] = Lrow[e];
            zg[i] = lg[i] - __logf(-__logf(Urow[e] + 1e-10f) + 1e-10f);
        }

        // plain top-1 (half max + argmax; feeds softmax and s_cnt)
        float pv1 = lg[0]; int pi1 = il;
        #pragma unroll
        for (int i = 1; i < 10; ++i) {
            const int e = il + 32 * i;
            if (better(lg[i], e, pv1, pi1)) { pv1 = lg[i]; pi1 = e; }
        }
        #pragma unroll
        for (int m = 1; m <= 16; m <<= 1) {
            const float ov = __shfl_xor(pv1, m);
            const int   oi = __shfl_xor(pi1, m);
            if (better(ov, oi, pv1, pi1)) { pv1 = ov; pi1 = oi; }
        }

        // gumbel top-3 over zg[]
        float g1 = -3.4e38f, g2 = -3.4e38f, g3 = -3.4e38f;
        int   j1 = 0x7ffffffd, j2 = 0x7ffffffe, j3 = 0x7fffffff;
        #pragma unroll
        for (int i = 0; i < 10; ++i) {
            const int e = il + 32 * i;
            const float z = zg[i];
            if (better(z, e, g1, j1)) { g3 = g2; j3 = j2; g2 = g1; j2 = j1; g1 = z; j1 = e; }
            else if (better(z, e, g2, j2)) { g3 = g2; j3 = j2; g2 = z; j2 = e; }
            else if (better(z, e, g3, j3)) { g3 = z; j3 = e; }
        }
        #pragma unroll
        for (int m = 1; m <= 16; m <<= 1) {
            const float o1 = __shfl_xor(g1, m); const int q1 = __shfl_xor(j1, m);
            const float o2 = __shfl_xor(g2, m); const int q2 = __shfl_xor(j2, m);
            const float o3 = __shfl_xor(g3, m); const int q3 = __shfl_xor(j3, m);
            if (better(o1, q1, g1, j1)) { g3 = g2; j3 = j2; g2 = g1; j2 = j1; g1 = o1; j1 = q1; }
            else if (better(o1, q1, g2, j2)) { g3 = g2; j3 = j2; g2 = o1; j2 = q1; }
            else if (better(o1, q1, g3, j3)) { g3 = o1; j3 = q1; }
            if (better(o2, q2, g2, j2)) { g3 = g2; j3 = j2; g2 = o2; j2 = q2; }
            else if (better(o2, q2, g3, j3)) { g3 = o2; j3 = q2; }
            if (better(o3, q3, g3, j3)) { g3 = o3; j3 = q3; }
        }

        // flag gumbel near-ties for the fp64 fixup
        if (il == 0 && g1 - g2 < MARGIN) {
            unsigned ix = atomicAdd(nflag, 1u);
            if (ix < FLAGCAP)
                flags[ix] = make_uint2((unsigned)n | ((unsigned)h << 16),
                                       (unsigned)j1 | ((unsigned)j2 << 9) |
                                       ((unsigned)j3 << 18));
        }

        // softmax over this (row, codebook)
        float s = 0.f, ex[10];
        #pragma unroll
        for (int i = 0; i < 10; ++i) { ex[i] = __expf(lg[i] - pv1); s += ex[i]; }
        #pragma unroll
        for (int m = 1; m <= 16; m <<= 1) s += __shfl_xor(s, m);
        const float inv = 1.f / s;
        #pragma unroll
        for (int i = 0; i < 10; ++i) accp[i] += ex[i] * inv;

        if (il == 0) atomicAdd(&s_cnt[h * NE + pi1], 1u);

        // one-hot cb write (overwrites consumed logits row)
        #pragma unroll
        for (int i = 0; i < 10; ++i) {
            const int e = il + 32 * i;
            Lrow[e] = (e == j1) ? 1.f : 0.f;
        }
        // quantized gather
        const float* ent = entries + (size_t)(h * NE + j1) * DDIM;
        float* qrow = out + (size_t)n * ODIM + h * DDIM;
        #pragma unroll
        for (int j = 0; j < 12; ++j) {
            const int d = il + 32 * j;
            qrow[d] = ent[d];
        }
    }

    #pragma unroll
    for (int i = 0; i < 10; ++i)
        atomicAdd(&s_avgp[h * NE + il + 32 * i], accp[i]);
    __syncthreads();
    for (int i = tid; i < GE; i += 256) {
        atomicAdd(&gavgp[i], s_avgp[i]);
        unsigned int c = s_cnt[i];
        if (c) atomicAdd(&gcnt[i], c);
    }
}

// ---------------- Kernel B2: fp64 fixup of flagged gumbel near-ties -------
__global__ __launch_bounds__(256) void fixup_kernel(
    const float* __restrict__ X, const float* __restrict__ Wf,
    const float* __restrict__ bvec, const float* __restrict__ entries,
    const float* __restrict__ gumbel, float* __restrict__ out,
    const unsigned int* __restrict__ nflag, const uint2* __restrict__ flags)
{
    const int tid = threadIdx.x;
    const int wv = blockIdx.x * 4 + (tid >> 6);     // 1024 waves total
    const int lane = tid & 63;
    unsigned total = *nflag; if (total > FLAGCAP) total = FLAGCAP;

    for (unsigned f = wv; f < total; f += 1024) {
        const uint2 fl = flags[f];
        const int n  = fl.x & 0xffff;
        const int h  = (fl.x >> 16) & 1;
        const int c1 = fl.y & 511, c2 = (fl.y >> 9) & 511, c3 = (fl.y >> 18) & 511;

        const float* xr = X + (size_t)n * KDIM;
        const float* w1 = Wf + (size_t)(h * NE + c1) * KDIM;
        const float* w2 = Wf + (size_t)(h * NE + c2) * KDIM;
        const float* w3 = Wf + (size_t)(h * NE + c3) * KDIM;
        double d1 = 0.0, d2 = 0.0, d3 = 0.0;
        #pragma unroll
        for (int j = 0; j < 8; ++j) {
            const int k = lane + 64 * j;
            const double xv = (double)xr[k];
            d1 += xv * (double)w1[k];
            d2 += xv * (double)w2[k];
            d3 += xv * (double)w3[k];
        }
        #pragma unroll
        for (int m = 1; m <= 32; m <<= 1) {
            d1 += __shfl_xor(d1, m);
            d2 += __shfl_xor(d2, m);
            d3 += __shfl_xor(d3, m);
        }
        const float* Ur = gumbel + (size_t)(2 * n + h) * NE;
        d1 += (double)bvec[h * NE + c1] - log(-log((double)Ur[c1] + 1e-10) + 1e-10);
        d2 += (double)bvec[h * NE + c2] - log(-log((double)Ur[c2] + 1e-10) + 1e-10);
        d3 += (double)bvec[h * NE + c3] - log(-log((double)Ur[c3] + 1e-10) + 1e-10);

        int kb = c1; double db = d1;
        if (d2 > db || (d2 == db && c2 < kb)) { kb = c2; db = d2; }
        if (d3 > db || (d3 == db && c3 < kb)) { kb = c3; db = d3; }

        if (kb != c1) {
            float* Lrow = out + CB_OFF + (size_t)n * GE + h * NE;
            if (lane == 0) { Lrow[c1] = 0.f; Lrow[kb] = 1.f; }
            const float* ent = entries + (size_t)(h * NE + kb) * DDIM;
            float* qrow = out + (size_t)n * ODIM + h * DDIM;
            #pragma unroll
            for (int t = 0; t < 6; ++t) {
                const int d = lane + 64 * t;
                qrow[d] = ent[d];
            }
        }
    }
}

// ---------------- Kernel C: perplexity scalars ----------------------------
__global__ void finalize_kernel(const float* __restrict__ gavgp,
                                const unsigned int* __restrict__ gcnt,
                                float* __restrict__ out)
{
    __shared__ double sc[GE], sp[GE];
    const int t = threadIdx.x;
    if (t < GE) {
        double hp = (double)gcnt[t] * (1.0 / 48000.0);
        sc[t] = hp * log(hp + 1e-7);
        double ap = (double)gavgp[t] * (1.0 / 48000.0);
        sp[t] = ap * log(ap + 1e-7);
    }
    __syncthreads();
    if (t == 0) {
        double c0 = 0, c1 = 0, p0 = 0, p1 = 0;
        for (int e = 0; e < NE; ++e) { c0 += sc[e]; p0 += sp[e]; }
        for (int e = NE; e < GE; ++e) { c1 += sc[e]; p1 += sp[e]; }
        out[SC_OFF]     = (float)(exp(-c0) + exp(-c1));
        out[SC_OFF + 1] = (float)(exp(-p0) + exp(-p1));
    }
}

// ---------------- launch --------------------------------------------------
extern "C" void kernel_launch(void* const* d_in, const int* in_sizes, int n_in,
                              void* d_out, int out_size, void* d_ws, size_t ws_size,
                              hipStream_t stream)
{
    const float* X       = (const float*)d_in[0];
    const float* Wf      = (const float*)d_in[1];
    const float* bvec    = (const float*)d_in[2];
    const float* entries = (const float*)d_in[3];
    const float* gumbel  = (const float*)d_in[4];
    float* out = (float*)d_out;

    float* gavgp = (float*)d_ws;                                    // 2560 B
    unsigned int* gcnt = (unsigned int*)((char*)d_ws + 2560);       // 2560 B
    unsigned int* nflag = (unsigned int*)((char*)d_ws + 5120);      // 4 B
    uint2* flags = (uint2*)((char*)d_ws + 5632);                    // 128 KB
    _Float16* Wh = (_Float16*)((char*)d_ws + 139264);               // 640 KB

    hipMemsetAsync(d_ws, 0, 8192, stream);
    split_hi<<<160, 256, 0, stream>>>(Wf, Wh, 40960);               // 640*512/8
    gemm_cvt<<<1875, 256, 0, stream>>>(X, Wh, bvec, out + CB_OFF);
    epilogue_kernel<<<3000, 256, 0, stream>>>(entries, gumbel, out, gavgp,
                                              gcnt, nflag, flags);
    fixup_kernel<<<256, 256, 0, stream>>>(X, Wf, bvec, entries, gumbel, out,
                                          nflag, flags);
    finalize_kernel<<<1, 640, 0, stream>>>(gavgp, gcnt, out);
}

// Round 16
// 231.068 us; speedup vs baseline: 1.0572x; 1.0572x over previous
//
#include <hip/hip_runtime.h>
#include <math.h>
#include <stdint.h>

#define NROWS 48000
#define KDIM 512
#define NE 320
#define GE 640
#define DDIM 384
#define ODIM 768
#define CB_OFF 36864000ul
#define SC_OFF 67584000ul
// 1-pass f16 GEMM: logits ~= Xh @ Wh^T + b. Dropped terms Xl*W + Xh*Wl give
// logit error sigma ~6.4e-3 (gap error sigma ~9e-3). Gumbel argmax is the
// only exactness-critical decision (cb/quantized); near-ties (gap < MARGIN
// = 13 sigma) are re-resolved in fp64 over the top-3 by the fixup kernel.
// Plain argmax feeds only code_perplexity (threshold 12.4; ~3e-3/flip).
#define MARGIN 0.12f
#define FLAGCAP 16384u

using f16x8 = __attribute__((ext_vector_type(8))) _Float16;
using f32x4 = __attribute__((ext_vector_type(4))) float;

#define GLD16(gp, lp)                                                          \
    __builtin_amdgcn_global_load_lds(                                          \
        (const __attribute__((address_space(1))) uint32_t*)(gp),               \
        (__attribute__((address_space(3))) uint32_t*)(lp), 16, 0, 0)

// ---------------- W f32 -> f16 hi (0.65 MB) --------------------------------
__global__ __launch_bounds__(256) void split_hi(const float* __restrict__ src,
                                                _Float16* __restrict__ hi,
                                                int n8)
{
    int i = blockIdx.x * 256 + threadIdx.x;
    if (i >= n8) return;
    float4 v0 = *((const float4*)src + 2 * (size_t)i);
    float4 v1 = *((const float4*)src + 2 * (size_t)i + 1);
    float x[8] = {v0.x, v0.y, v0.z, v0.w, v1.x, v1.y, v1.z, v1.w};
    f16x8 h;
    #pragma unroll
    for (int k = 0; k < 8; ++k) h[k] = (_Float16)x[k];
    *(f16x8*)(hi + (size_t)i * 8) = h;
}

// ---------------- Kernel A: logits ~= Xh @ Wh^T + b (1-pass MFMA) ---------
__global__ __launch_bounds__(256) void gemm_cvt(
    const float* __restrict__ X,
    const _Float16* __restrict__ Wh,
    const float* __restrict__ bvec, float* __restrict__ Lout)
{
    __shared__ _Float16 lds[8192];              // 16 KB: Ah|Bh, each [128][32]
    _Float16* Ahs = lds;
    _Float16* Bhs = lds + 4096;

    // bijective XCD swizzle (nwg=1875): q8=234, r8=3
    const int bid = blockIdx.x;
    const int q8 = 1875 / 8, r8 = 1875 % 8;
    const int xcd = bid & 7, wi = bid >> 3;
    const int wg = (xcd < r8 ? xcd * (q8 + 1) : r8 * (q8 + 1) + (xcd - r8) * q8) + wi;
    const int bm = wg / 5, bn = wg % 5;

    const int tid = threadIdx.x;
    const int wid = tid >> 6, lane = tid & 63;
    const int fr = lane & 15, fq = lane >> 4;
    const int wm = (wid >> 1) * 64, wn = (wid & 1) * 64;

    const float*     Ag  = X  + (size_t)(bm * 128) * KDIM;
    const _Float16*  Bhg = Wh + (size_t)(bn * 128) * KDIM;

    f32x4 acc[4][4];
    #pragma unroll
    for (int i = 0; i < 4; ++i)
        #pragma unroll
        for (int j = 0; j < 4; ++j)
            acc[i][j] = (f32x4){0.f, 0.f, 0.f, 0.f};

    for (int kk = 0; kk < 16; ++kk) {
        const int kh = kk * 32;
        // B staging via GLD16 (2 per lane)
        #pragma unroll
        for (int q = 0; q < 2; ++q) {
            const int c = wid * 2 + q;
            const int srow = lane >> 2, sc8 = (lane & 3) * 8;
            const size_t go = (size_t)(c * 16 + srow) * KDIM + kh + sc8;
            GLD16(Bhg + go, Bhs + c * 512);
        }
        // A staging: f32 -> f16 hi in-register -> LDS
        #pragma unroll
        for (int c = 0; c < 2; ++c) {
            const int idx8 = c * 256 + tid;
            const int row = idx8 >> 2, k8 = (idx8 & 3) * 8;
            const float4* xp = (const float4*)(Ag + (size_t)row * KDIM + kh + k8);
            float4 v0 = xp[0], v1 = xp[1];
            float xs[8] = {v0.x, v0.y, v0.z, v0.w, v1.x, v1.y, v1.z, v1.w};
            f16x8 h;
            #pragma unroll
            for (int q = 0; q < 8; ++q) h[q] = (_Float16)xs[q];
            *(f16x8*)&Ahs[row * 32 + k8] = h;
        }
        __syncthreads();

        f16x8 ah[4], bh[4];
        #pragma unroll
        for (int i = 0; i < 4; ++i) {
            const int ro = (wm + i * 16 + fr) * 32 + fq * 8;
            ah[i] = *(const f16x8*)&Ahs[ro];
            const int co = (wn + i * 16 + fr) * 32 + fq * 8;
            bh[i] = *(const f16x8*)&Bhs[co];
        }
        #pragma unroll
        for (int i = 0; i < 4; ++i)
            #pragma unroll
            for (int j = 0; j < 4; ++j)
                acc[i][j] = __builtin_amdgcn_mfma_f32_16x16x32_f16(ah[i], bh[j], acc[i][j], 0, 0, 0);
        __syncthreads();
    }

    // C/D layout: col = lane&15, row = (lane>>4)*4 + reg   [m89-verified]
    #pragma unroll
    for (int i = 0; i < 4; ++i) {
        #pragma unroll
        for (int r = 0; r < 4; ++r) {
            const int m = bm * 128 + wm + i * 16 + fq * 4 + r;
            float* orow = Lout + (size_t)m * GE + bn * 128 + wn;
            #pragma unroll
            for (int j = 0; j < 4; ++j) {
                const int n = bn * 128 + wn + j * 16 + fr;
                orow[j * 16 + fr] = acc[i][j][r] + bvec[n];
            }
        }
    }
}

// ---------------- helpers -------------------------------------------------
__device__ __forceinline__ bool better(float a, int ia, float b, int ib) {
    return (a > b) || (a == b && ia < ib);
}

// ---------------- Kernel B: epilogue (R14 shape, top-2 bfly + rare 3rd) ---
__global__ __launch_bounds__(256) void epilogue_kernel(
    const float* __restrict__ entries, const float* __restrict__ gumbel,
    float* __restrict__ out, float* __restrict__ gavgp,
    unsigned int* __restrict__ gcnt, unsigned int* __restrict__ nflag,
    uint2* __restrict__ flags)
{
    __shared__ float s_avgp[GE];
    __shared__ unsigned int s_cnt[GE];
    const int tid = threadIdx.x;
    for (int i = tid; i < GE; i += 256) { s_avgp[i] = 0.f; s_cnt[i] = 0u; }
    __syncthreads();

    const int wave = tid >> 6, lane = tid & 63;
    const int h = lane >> 5, il = lane & 31;

    float accp[10];
    #pragma unroll
    for (int i = 0; i < 10; ++i) accp[i] = 0.f;

    float* cb = out + CB_OFF;

    for (int rr = 0; rr < 8; ++rr) {
        const int n = blockIdx.x * 32 + wave * 8 + rr;
        float* Lrow = cb + (size_t)n * GE + h * NE;
        const float* Urow = gumbel + (size_t)(2 * n + h) * NE;

        // parallel load + trans loop: no cross-iteration deps
        float lg[10], zg[10];
        #pragma unroll
        for (int i = 0; i < 10; ++i) {
            const int e = il + 32 * i;
            lg[i] = Lrow[e];
            zg[i] = lg[i] - __logf(-__logf(Urow[e] + 1e-10f) + 1e-10f);
        }

        // plain top-1 (half max + argmax; feeds softmax and s_cnt)
        float pv1 = lg[0]; int pi1 = il;
        #pragma unroll
        for (int i = 1; i < 10; ++i) {
            const int e = il + 32 * i;
            if (better(lg[i], e, pv1, pi1)) { pv1 = lg[i]; pi1 = e; }
        }
        #pragma unroll
        for (int m = 1; m <= 16; m <<= 1) {
            const float ov = __shfl_xor(pv1, m);
            const int   oi = __shfl_xor(pi1, m);
            if (better(ov, oi, pv1, pi1)) { pv1 = ov; pi1 = oi; }
        }

        // gumbel: local sorted top-3 (kept for rare 3rd extraction)
        float l1 = -3.4e38f, l2 = -3.4e38f, l3 = -3.4e38f;
        int   li1 = 0x7ffffffd, li2 = 0x7ffffffe, li3 = 0x7fffffff;
        #pragma unroll
        for (int i = 0; i < 10; ++i) {
            const int e = il + 32 * i;
            const float z = zg[i];
            if (better(z, e, l1, li1)) { l3 = l2; li3 = li2; l2 = l1; li2 = li1; l1 = z; li1 = e; }
            else if (better(z, e, l2, li2)) { l3 = l2; li3 = li2; l2 = z; li2 = e; }
            else if (better(z, e, l3, li3)) { l3 = z; li3 = e; }
        }
        // top-2 butterfly (4 shfl + light merge per step; R5-proven t2merge)
        float g1 = l1, g2 = l2; int j1 = li1, j2 = li2;
        #pragma unroll
        for (int m = 1; m <= 16; m <<= 1) {
            const float o1 = __shfl_xor(g1, m); const int q1 = __shfl_xor(j1, m);
            const float o2 = __shfl_xor(g2, m); const int q2 = __shfl_xor(j2, m);
            if (better(o1, q1, g1, j1)) {
                const float tv = g1; const int ti = j1;
                g1 = o1; j1 = q1;
                if (better(o2, q2, tv, ti)) { g2 = o2; j2 = q2; }
                else                        { g2 = tv; j2 = ti; }
            } else if (better(o1, q1, g2, j2)) {
                g2 = o1; j2 = q1;
            }
        }

        // rare near-tie: extract global 3rd and flag (branch is half-wave
        // uniform; shfl partners (mask<=16) stay inside the executing half)
        if (g1 - g2 < MARGIN) {
            float c; int ci;
            if (li1 != j1 && li1 != j2)      { c = l1; ci = li1; }
            else if (li2 != j1 && li2 != j2) { c = l2; ci = li2; }
            else                             { c = l3; ci = li3; }
            #pragma unroll
            for (int m = 1; m <= 16; m <<= 1) {
                const float oc = __shfl_xor(c, m);
                const int   oi = __shfl_xor(ci, m);
                if (better(oc, oi, c, ci)) { c = oc; ci = oi; }
            }
            if (il == 0) {
                unsigned ix = atomicAdd(nflag, 1u);
                if (ix < FLAGCAP)
                    flags[ix] = make_uint2((unsigned)n | ((unsigned)h << 16),
                                           (unsigned)j1 | ((unsigned)j2 << 9) |
                                           ((unsigned)ci << 18));
            }
        }

        // softmax over this (row, codebook)
        float s = 0.f, ex[10];
        #pragma unroll
        for (int i = 0; i < 10; ++i) { ex[i] = __expf(lg[i] - pv1); s += ex[i]; }
        #pragma unroll
        for (int m = 1; m <= 16; m <<= 1) s += __shfl_xor(s, m);
        const float inv = 1.f / s;
        #pragma unroll
        for (int i = 0; i < 10; ++i) accp[i] += ex[i] * inv;

        if (il == 0) atomicAdd(&s_cnt[h * NE + pi1], 1u);

        // one-hot cb write (overwrites consumed logits row)
        #pragma unroll
        for (int i = 0; i < 10; ++i) {
            const int e = il + 32 * i;
            Lrow[e] = (e == j1) ? 1.f : 0.f;
        }
        // quantized gather
        const float* ent = entries + (size_t)(h * NE + j1) * DDIM;
        float* qrow = out + (size_t)n * ODIM + h * DDIM;
        #pragma unroll
        for (int j = 0; j < 12; ++j) {
            const int d = il + 32 * j;
            qrow[d] = ent[d];
        }
    }

    #pragma unroll
    for (int i = 0; i < 10; ++i)
        atomicAdd(&s_avgp[h * NE + il + 32 * i], accp[i]);
    __syncthreads();
    for (int i = tid; i < GE; i += 256) {
        atomicAdd(&gavgp[i], s_avgp[i]);
        unsigned int c = s_cnt[i];
        if (c) atomicAdd(&gcnt[i], c);
    }
}

// ---------------- Kernel B2: fp64 fixup of flagged gumbel near-ties -------
__global__ __launch_bounds__(256) void fixup_kernel(
    const float* __restrict__ X, const float* __restrict__ Wf,
    const float* __restrict__ bvec, const float* __restrict__ entries,
    const float* __restrict__ gumbel, float* __restrict__ out,
    const unsigned int* __restrict__ nflag, const uint2* __restrict__ flags)
{
    const int tid = threadIdx.x;
    const int wv = blockIdx.x * 4 + (tid >> 6);     // 1024 waves total
    const int lane = tid & 63;
    unsigned total = *nflag; if (total > FLAGCAP) total = FLAGCAP;

    for (unsigned f = wv; f < total; f += 1024) {
        const uint2 fl = flags[f];
        const int n  = fl.x & 0xffff;
        const int h  = (fl.x >> 16) & 1;
        const int c1 = fl.y & 511, c2 = (fl.y >> 9) & 511, c3 = (fl.y >> 18) & 511;

        const float* xr = X + (size_t)n * KDIM;
        const float* w1 = Wf + (size_t)(h * NE + c1) * KDIM;
        const float* w2 = Wf + (size_t)(h * NE + c2) * KDIM;
        const float* w3 = Wf + (size_t)(h * NE + c3) * KDIM;
        double d1 = 0.0, d2 = 0.0, d3 = 0.0;
        #pragma unroll
        for (int j = 0; j < 8; ++j) {
            const int k = lane + 64 * j;
            const double xv = (double)xr[k];
            d1 += xv * (double)w1[k];
            d2 += xv * (double)w2[k];
            d3 += xv * (double)w3[k];
        }
        #pragma unroll
        for (int m = 1; m <= 32; m <<= 1) {
            d1 += __shfl_xor(d1, m);
            d2 += __shfl_xor(d2, m);
            d3 += __shfl_xor(d3, m);
        }
        const float* Ur = gumbel + (size_t)(2 * n + h) * NE;
        d1 += (double)bvec[h * NE + c1] - log(-log((double)Ur[c1] + 1e-10) + 1e-10);
        d2 += (double)bvec[h * NE + c2] - log(-log((double)Ur[c2] + 1e-10) + 1e-10);
        d3 += (double)bvec[h * NE + c3] - log(-log((double)Ur[c3] + 1e-10) + 1e-10);

        int kb = c1; double db = d1;
        if (d2 > db || (d2 == db && c2 < kb)) { kb = c2; db = d2; }
        if (d3 > db || (d3 == db && c3 < kb)) { kb = c3; db = d3; }

        if (kb != c1) {
            float* Lrow = out + CB_OFF + (size_t)n * GE + h * NE;
            if (lane == 0) { Lrow[c1] = 0.f; Lrow[kb] = 1.f; }
            const float* ent = entries + (size_t)(h * NE + kb) * DDIM;
            float* qrow = out + (size_t)n * ODIM + h * DDIM;
            #pragma unroll
            for (int t = 0; t < 6; ++t) {
                const int d = lane + 64 * t;
                qrow[d] = ent[d];
            }
        }
    }
}

// ---------------- Kernel C: perplexity scalars ----------------------------
__global__ void finalize_kernel(const float* __restrict__ gavgp,
                                const unsigned int* __restrict__ gcnt,
                                float* __restrict__ out)
{
    __shared__ double sc[GE], sp[GE];
    const int t = threadIdx.x;
    if (t < GE) {
        double hp = (double)gcnt[t] * (1.0 / 48000.0);
        sc[t] = hp * log(hp + 1e-7);
        double ap = (double)gavgp[t] * (1.0 / 48000.0);
        sp[t] = ap * log(ap + 1e-7);
    }
    __syncthreads();
    if (t == 0) {
        double c0 = 0, c1 = 0, p0 = 0, p1 = 0;
        for (int e = 0; e < NE; ++e) { c0 += sc[e]; p0 += sp[e]; }
        for (int e = NE; e < GE; ++e) { c1 += sc[e]; p1 += sp[e]; }
        out[SC_OFF]     = (float)(exp(-c0) + exp(-c1));
        out[SC_OFF + 1] = (float)(exp(-p0) + exp(-p1));
    }
}

// ---------------- launch --------------------------------------------------
extern "C" void kernel_launch(void* const* d_in, const int* in_sizes, int n_in,
                              void* d_out, int out_size, void* d_ws, size_t ws_size,
                              hipStream_t stream)
{
    const float* X       = (const float*)d_in[0];
    const float* Wf      = (const float*)d_in[1];
    const float* bvec    = (const float*)d_in[2];
    const float* entries = (const float*)d_in[3];
    const float* gumbel  = (const float*)d_in[4];
    float* out = (float*)d_out;

    float* gavgp = (float*)d_ws;                                    // 2560 B
    unsigned int* gcnt = (unsigned int*)((char*)d_ws + 2560);       // 2560 B
    unsigned int* nflag = (unsigned int*)((char*)d_ws + 5120);      // 4 B
    uint2* flags = (uint2*)((char*)d_ws + 5632);                    // 128 KB
    _Float16* Wh = (_Float16*)((char*)d_ws + 139264);               // 640 KB

    hipMemsetAsync(d_ws, 0, 8192, stream);
    split_hi<<<160, 256, 0, stream>>>(Wf, Wh, 40960);               // 640*512/8
    gemm_cvt<<<1875, 256, 0, stream>>>(X, Wh, bvec, out + CB_OFF);
    epilogue_kernel<<<1500, 256, 0, stream>>>(entries, gumbel, out, gavgp,
                                              gcnt, nflag, flags);
    fixup_kernel<<<256, 256, 0, stream>>>(X, Wf, bvec, entries, gumbel, out,
                                          nflag, flags);
    finalize_kernel<<<1, 640, 0, stream>>>(gavgp, gcnt, out);
}

// Round 17
// 228.299 us; speedup vs baseline: 1.0701x; 1.0121x over previous
//
#include <hip/hip_runtime.h>
#include <math.h>
#include <stdint.h>

#define NROWS 48000
#define KDIM 512
#define NE 320
#define GE 640
#define DDIM 384
#define ODIM 768
#define CB_OFF 36864000ul
#define SC_OFF 67584000ul
// 1-pass f16 GEMM: logits ~= Xh @ Wh^T + b. Dropped terms Xl*W + Xh*Wl give
// logit error sigma ~6.4e-3 (gap error sigma ~9e-3). Gumbel argmax is the
// only exactness-critical decision (cb/quantized); near-ties (gap < MARGIN
// = 13 sigma) are re-resolved in fp64 over the top-3 in the epilogue's
// cold post-loop section (flags are block-local: max 64 = 32 rows x 2 cb).
// Plain argmax feeds only code_perplexity (threshold 12.4; ~3e-3/flip).
#define MARGIN 0.12f

using f16x8 = __attribute__((ext_vector_type(8))) _Float16;
using f32x4 = __attribute__((ext_vector_type(4))) float;

#define GLD16(gp, lp)                                                          \
    __builtin_amdgcn_global_load_lds(                                          \
        (const __attribute__((address_space(1))) uint32_t*)(gp),               \
        (__attribute__((address_space(3))) uint32_t*)(lp), 16, 0, 0)

// ---------------- W f32 -> f16 hi (0.65 MB) --------------------------------
__global__ __launch_bounds__(256) void split_hi(const float* __restrict__ src,
                                                _Float16* __restrict__ hi,
                                                int n8)
{
    int i = blockIdx.x * 256 + threadIdx.x;
    if (i >= n8) return;
    float4 v0 = *((const float4*)src + 2 * (size_t)i);
    float4 v1 = *((const float4*)src + 2 * (size_t)i + 1);
    float x[8] = {v0.x, v0.y, v0.z, v0.w, v1.x, v1.y, v1.z, v1.w};
    f16x8 h;
    #pragma unroll
    for (int k = 0; k < 8; ++k) h[k] = (_Float16)x[k];
    *(f16x8*)(hi + (size_t)i * 8) = h;
}

// ---------------- Kernel A: logits ~= Xh @ Wh^T + b (1-pass MFMA) ---------
__global__ __launch_bounds__(256) void gemm_cvt(
    const float* __restrict__ X,
    const _Float16* __restrict__ Wh,
    const float* __restrict__ bvec, float* __restrict__ Lout)
{
    __shared__ _Float16 lds[8192];              // 16 KB: Ah|Bh, each [128][32]
    _Float16* Ahs = lds;
    _Float16* Bhs = lds + 4096;

    // bijective XCD swizzle (nwg=1875): q8=234, r8=3
    const int bid = blockIdx.x;
    const int q8 = 1875 / 8, r8 = 1875 % 8;
    const int xcd = bid & 7, wi = bid >> 3;
    const int wg = (xcd < r8 ? xcd * (q8 + 1) : r8 * (q8 + 1) + (xcd - r8) * q8) + wi;
    const int bm = wg / 5, bn = wg % 5;

    const int tid = threadIdx.x;
    const int wid = tid >> 6, lane = tid & 63;
    const int fr = lane & 15, fq = lane >> 4;
    const int wm = (wid >> 1) * 64, wn = (wid & 1) * 64;

    const float*     Ag  = X  + (size_t)(bm * 128) * KDIM;
    const _Float16*  Bhg = Wh + (size_t)(bn * 128) * KDIM;

    f32x4 acc[4][4];
    #pragma unroll
    for (int i = 0; i < 4; ++i)
        #pragma unroll
        for (int j = 0; j < 4; ++j)
            acc[i][j] = (f32x4){0.f, 0.f, 0.f, 0.f};

    for (int kk = 0; kk < 16; ++kk) {
        const int kh = kk * 32;
        // B staging via GLD16 (2 per lane)
        #pragma unroll
        for (int q = 0; q < 2; ++q) {
            const int c = wid * 2 + q;
            const int srow = lane >> 2, sc8 = (lane & 3) * 8;
            const size_t go = (size_t)(c * 16 + srow) * KDIM + kh + sc8;
            GLD16(Bhg + go, Bhs + c * 512);
        }
        // A staging: f32 -> f16 hi in-register -> LDS
        #pragma unroll
        for (int c = 0; c < 2; ++c) {
            const int idx8 = c * 256 + tid;
            const int row = idx8 >> 2, k8 = (idx8 & 3) * 8;
            const float4* xp = (const float4*)(Ag + (size_t)row * KDIM + kh + k8);
            float4 v0 = xp[0], v1 = xp[1];
            float xs[8] = {v0.x, v0.y, v0.z, v0.w, v1.x, v1.y, v1.z, v1.w};
            f16x8 h;
            #pragma unroll
            for (int q = 0; q < 8; ++q) h[q] = (_Float16)xs[q];
            *(f16x8*)&Ahs[row * 32 + k8] = h;
        }
        __syncthreads();

        f16x8 ah[4], bh[4];
        #pragma unroll
        for (int i = 0; i < 4; ++i) {
            const int ro = (wm + i * 16 + fr) * 32 + fq * 8;
            ah[i] = *(const f16x8*)&Ahs[ro];
            const int co = (wn + i * 16 + fr) * 32 + fq * 8;
            bh[i] = *(const f16x8*)&Bhs[co];
        }
        #pragma unroll
        for (int i = 0; i < 4; ++i)
            #pragma unroll
            for (int j = 0; j < 4; ++j)
                acc[i][j] = __builtin_amdgcn_mfma_f32_16x16x32_f16(ah[i], bh[j], acc[i][j], 0, 0, 0);
        __syncthreads();
    }

    // C/D layout: col = lane&15, row = (lane>>4)*4 + reg   [m89-verified]
    #pragma unroll
    for (int i = 0; i < 4; ++i) {
        #pragma unroll
        for (int r = 0; r < 4; ++r) {
            const int m = bm * 128 + wm + i * 16 + fq * 4 + r;
            float* orow = Lout + (size_t)m * GE + bn * 128 + wn;
            #pragma unroll
            for (int j = 0; j < 4; ++j) {
                const int n = bn * 128 + wn + j * 16 + fr;
                orow[j * 16 + fr] = acc[i][j][r] + bvec[n];
            }
        }
    }
}

// ---------------- helpers -------------------------------------------------
__device__ __forceinline__ bool better(float a, int ia, float b, int ib) {
    return (a > b) || (a == b && ia < ib);
}

// ---------------- Kernel B: epilogue + block-local fp64 fixup -------------
__global__ __launch_bounds__(256) void epilogue_kernel(
    const float* __restrict__ X, const float* __restrict__ Wf,
    const float* __restrict__ bvec,
    const float* __restrict__ entries, const float* __restrict__ gumbel,
    float* __restrict__ out, float* __restrict__ gavgp,
    unsigned int* __restrict__ gcnt)
{
    __shared__ float s_avgp[GE];
    __shared__ unsigned int s_cnt[GE];
    __shared__ unsigned int s_nflag;
    __shared__ uint2 s_flags[64];               // exact cap: 32 rows x 2 cb
    const int tid = threadIdx.x;
    for (int i = tid; i < GE; i += 256) { s_avgp[i] = 0.f; s_cnt[i] = 0u; }
    if (tid == 0) s_nflag = 0u;
    __syncthreads();

    const int wave = tid >> 6, lane = tid & 63;
    const int h = lane >> 5, il = lane & 31;

    float accp[10];
    #pragma unroll
    for (int i = 0; i < 10; ++i) accp[i] = 0.f;

    float* cb = out + CB_OFF;

    for (int rr = 0; rr < 8; ++rr) {
        const int n = blockIdx.x * 32 + wave * 8 + rr;
        float* Lrow = cb + (size_t)n * GE + h * NE;
        const float* Urow = gumbel + (size_t)(2 * n + h) * NE;

        // parallel load + trans loop: no cross-iteration deps
        float lg[10], zg[10];
        #pragma unroll
        for (int i = 0; i < 10; ++i) {
            const int e = il + 32 * i;
            lg[i] = Lrow[e];
            zg[i] = lg[i] - __logf(-__logf(Urow[e] + 1e-10f) + 1e-10f);
        }

        // plain top-1 (half max + argmax; feeds softmax and s_cnt)
        float pv1 = lg[0]; int pi1 = il;
        #pragma unroll
        for (int i = 1; i < 10; ++i) {
            const int e = il + 32 * i;
            if (better(lg[i], e, pv1, pi1)) { pv1 = lg[i]; pi1 = e; }
        }
        #pragma unroll
        for (int m = 1; m <= 16; m <<= 1) {
            const float ov = __shfl_xor(pv1, m);
            const int   oi = __shfl_xor(pi1, m);
            if (better(ov, oi, pv1, pi1)) { pv1 = ov; pi1 = oi; }
        }

        // gumbel: local sorted top-3 (kept for rare 3rd extraction)
        float l1 = -3.4e38f, l2 = -3.4e38f, l3 = -3.4e38f;
        int   li1 = 0x7ffffffd, li2 = 0x7ffffffe, li3 = 0x7fffffff;
        #pragma unroll
        for (int i = 0; i < 10; ++i) {
            const int e = il + 32 * i;
            const float z = zg[i];
            if (better(z, e, l1, li1)) { l3 = l2; li3 = li2; l2 = l1; li2 = li1; l1 = z; li1 = e; }
            else if (better(z, e, l2, li2)) { l3 = l2; li3 = li2; l2 = z; li2 = e; }
            else if (better(z, e, l3, li3)) { l3 = z; li3 = e; }
        }
        // top-2 butterfly (4 shfl + light merge per step)
        float g1 = l1, g2 = l2; int j1 = li1, j2 = li2;
        #pragma unroll
        for (int m = 1; m <= 16; m <<= 1) {
            const float o1 = __shfl_xor(g1, m); const int q1 = __shfl_xor(j1, m);
            const float o2 = __shfl_xor(g2, m); const int q2 = __shfl_xor(j2, m);
            if (better(o1, q1, g1, j1)) {
                const float tv = g1; const int ti = j1;
                g1 = o1; j1 = q1;
                if (better(o2, q2, tv, ti)) { g2 = o2; j2 = q2; }
                else                        { g2 = tv; j2 = ti; }
            } else if (better(o1, q1, g2, j2)) {
                g2 = o1; j2 = q1;
            }
        }

        // rare near-tie: extract global 3rd, flag into block-local LDS list
        if (g1 - g2 < MARGIN) {
            float c; int ci;
            if (li1 != j1 && li1 != j2)      { c = l1; ci = li1; }
            else if (li2 != j1 && li2 != j2) { c = l2; ci = li2; }
            else                             { c = l3; ci = li3; }
            #pragma unroll
            for (int m = 1; m <= 16; m <<= 1) {
                const float oc = __shfl_xor(c, m);
                const int   oi = __shfl_xor(ci, m);
                if (better(oc, oi, c, ci)) { c = oc; ci = oi; }
            }
            if (il == 0) {
                unsigned ix = atomicAdd(&s_nflag, 1u);
                if (ix < 64u)
                    s_flags[ix] = make_uint2((unsigned)n | ((unsigned)h << 16),
                                             (unsigned)j1 | ((unsigned)j2 << 9) |
                                             ((unsigned)ci << 18));
            }
        }

        // softmax over this (row, codebook)
        float s = 0.f, ex[10];
        #pragma unroll
        for (int i = 0; i < 10; ++i) { ex[i] = __expf(lg[i] - pv1); s += ex[i]; }
        #pragma unroll
        for (int m = 1; m <= 16; m <<= 1) s += __shfl_xor(s, m);
        const float inv = 1.f / s;
        #pragma unroll
        for (int i = 0; i < 10; ++i) accp[i] += ex[i] * inv;

        if (il == 0) atomicAdd(&s_cnt[h * NE + pi1], 1u);

        // one-hot cb write (overwrites consumed logits row)
        #pragma unroll
        for (int i = 0; i < 10; ++i) {
            const int e = il + 32 * i;
            Lrow[e] = (e == j1) ? 1.f : 0.f;
        }
        // quantized gather
        const float* ent = entries + (size_t)(h * NE + j1) * DDIM;
        float* qrow = out + (size_t)n * ODIM + h * DDIM;
        #pragma unroll
        for (int j = 0; j < 12; ++j) {
            const int d = il + 32 * j;
            qrow[d] = ent[d];
        }
    }

    #pragma unroll
    for (int i = 0; i < 10; ++i)
        atomicAdd(&s_avgp[h * NE + il + 32 * i], accp[i]);
    __syncthreads();                 // drains hot-loop stores + flag list
    for (int i = tid; i < GE; i += 256) {
        atomicAdd(&gavgp[i], s_avgp[i]);
        unsigned int c = s_cnt[i];
        if (c) atomicAdd(&gcnt[i], c);
    }

    // ---- cold path: fp64 re-resolve of this block's flagged near-ties ----
    unsigned nf = s_nflag; if (nf > 64u) nf = 64u;
    for (unsigned f = wave; f < nf; f += 4) {
        const uint2 fl = s_flags[f];
        const int n  = fl.x & 0xffff;
        const int hh = (fl.x >> 16) & 1;
        const int c1 = fl.y & 511, c2 = (fl.y >> 9) & 511, c3 = (fl.y >> 18) & 511;

        const float* xr = X + (size_t)n * KDIM;
        const float* w1 = Wf + (size_t)(hh * NE + c1) * KDIM;
        const float* w2 = Wf + (size_t)(hh * NE + c2) * KDIM;
        const float* w3 = Wf + (size_t)(hh * NE + c3) * KDIM;
        double d1 = 0.0, d2 = 0.0, d3 = 0.0;
        #pragma unroll
        for (int j = 0; j < 8; ++j) {
            const int k = lane + 64 * j;
            const double xv = (double)xr[k];
            d1 += xv * (double)w1[k];
            d2 += xv * (double)w2[k];
            d3 += xv * (double)w3[k];
        }
        #pragma unroll
        for (int m = 1; m <= 32; m <<= 1) {
            d1 += __shfl_xor(d1, m);
            d2 += __shfl_xor(d2, m);
            d3 += __shfl_xor(d3, m);
        }
        const float* Ur = gumbel + (size_t)(2 * n + hh) * NE;
        d1 += (double)bvec[hh * NE + c1] - log(-log((double)Ur[c1] + 1e-10) + 1e-10);
        d2 += (double)bvec[hh * NE + c2] - log(-log((double)Ur[c2] + 1e-10) + 1e-10);
        d3 += (double)bvec[hh * NE + c3] - log(-log((double)Ur[c3] + 1e-10) + 1e-10);

        int kb = c1; double db = d1;
        if (d2 > db || (d2 == db && c2 < kb)) { kb = c2; db = d2; }
        if (d3 > db || (d3 == db && c3 < kb)) { kb = c3; db = d3; }

        if (kb != c1) {
            float* Lrow = cb + (size_t)n * GE + hh * NE;
            if (lane == 0) { Lrow[c1] = 0.f; Lrow[kb] = 1.f; }
            const float* ent = entries + (size_t)(hh * NE + kb) * DDIM;
            float* qrow = out + (size_t)n * ODIM + hh * DDIM;
            #pragma unroll
            for (int t = 0; t < 6; ++t) {
                const int d = lane + 64 * t;
                qrow[d] = ent[d];
            }
        }
    }
}

// ---------------- Kernel C: perplexity scalars ----------------------------
__global__ void finalize_kernel(const float* __restrict__ gavgp,
                                const unsigned int* __restrict__ gcnt,
                                float* __restrict__ out)
{
    __shared__ double sc[GE], sp[GE];
    const int t = threadIdx.x;
    if (t < GE) {
        double hp = (double)gcnt[t] * (1.0 / 48000.0);
        sc[t] = hp * log(hp + 1e-7);
        double ap = (double)gavgp[t] * (1.0 / 48000.0);
        sp[t] = ap * log(ap + 1e-7);
    }
    __syncthreads();
    if (t == 0) {
        double c0 = 0, c1 = 0, p0 = 0, p1 = 0;
        for (int e = 0; e < NE; ++e) { c0 += sc[e]; p0 += sp[e]; }
        for (int e = NE; e < GE; ++e) { c1 += sc[e]; p1 += sp[e]; }
        out[SC_OFF]     = (float)(exp(-c0) + exp(-c1));
        out[SC_OFF + 1] = (float)(exp(-p0) + exp(-p1));
    }
}

// ---------------- launch --------------------------------------------------
extern "C" void kernel_launch(void* const* d_in, const int* in_sizes, int n_in,
                              void* d_out, int out_size, void* d_ws, size_t ws_size,
                              hipStream_t stream)
{
    const float* X       = (const float*)d_in[0];
    const float* Wf      = (const float*)d_in[1];
    const float* bvec    = (const float*)d_in[2];
    const float* entries = (const float*)d_in[3];
    const float* gumbel  = (const float*)d_in[4];
    float* out = (float*)d_out;

    float* gavgp = (float*)d_ws;                                    // 2560 B
    unsigned int* gcnt = (unsigned int*)((char*)d_ws + 2560);       // 2560 B
    _Float16* Wh = (_Float16*)((char*)d_ws + 8192);                 // 640 KB

    hipMemsetAsync(d_ws, 0, 8192, stream);
    split_hi<<<160, 256, 0, stream>>>(Wf, Wh, 40960);               // 640*512/8
    gemm_cvt<<<1875, 256, 0, stream>>>(X, Wh, bvec, out + CB_OFF);
    epilogue_kernel<<<1500, 256, 0, stream>>>(X, Wf, bvec, entries, gumbel,
                                              out, gavgp, gcnt);
    finalize_kernel<<<1, 640, 0, stream>>>(gavgp, gcnt, out);
}

// Round 18
// 226.827 us; speedup vs baseline: 1.0770x; 1.0065x over previous
//
#include <hip/hip_runtime.h>
#include <math.h>
#include <stdint.h>

#define NROWS 48000
#define KDIM 512
#define NE 320
#define GE 640
#define DDIM 384
#define ODIM 768
#define CB_OFF 36864000ul
#define SC_OFF 67584000ul
// 1-pass f16 GEMM: logits ~= Xh @ Wh^T + b. Dropped terms Xl*W + Xh*Wl give
// logit error sigma ~6.4e-3 (gap error sigma ~9e-3). Gumbel argmax is the
// only exactness-critical decision (cb/quantized); near-ties (gap < MARGIN
// = 13 sigma) are re-resolved in fp64 over the top-3 in the epilogue's
// cold post-loop section (flags are block-local: max 64 = 32 rows x 2 cb).
// Plain argmax feeds only code_perplexity (threshold 12.4; ~3e-3/flip).
#define MARGIN 0.12f

using f16x8 = __attribute__((ext_vector_type(8))) _Float16;
using f32x4 = __attribute__((ext_vector_type(4))) float;

#define GLD16(gp, lp)                                                          \
    __builtin_amdgcn_global_load_lds(                                          \
        (const __attribute__((address_space(1))) uint32_t*)(gp),               \
        (__attribute__((address_space(3))) uint32_t*)(lp), 16, 0, 0)

// ---------------- W f32 -> f16 hi (0.65 MB) --------------------------------
__global__ __launch_bounds__(256) void split_hi(const float* __restrict__ src,
                                                _Float16* __restrict__ hi,
                                                int n8)
{
    int i = blockIdx.x * 256 + threadIdx.x;
    if (i >= n8) return;
    float4 v0 = *((const float4*)src + 2 * (size_t)i);
    float4 v1 = *((const float4*)src + 2 * (size_t)i + 1);
    float x[8] = {v0.x, v0.y, v0.z, v0.w, v1.x, v1.y, v1.z, v1.w};
    f16x8 h;
    #pragma unroll
    for (int k = 0; k < 8; ++k) h[k] = (_Float16)x[k];
    *(f16x8*)(hi + (size_t)i * 8) = h;
}

// ---------------- Kernel A: logits ~= Xh @ Wh^T + b (1-pass MFMA) ---------
__global__ __launch_bounds__(256) void gemm_cvt(
    const float* __restrict__ X,
    const _Float16* __restrict__ Wh,
    const float* __restrict__ bvec, float* __restrict__ Lout)
{
    __shared__ _Float16 lds[8192];              // 16 KB: Ah|Bh, each [128][32]
    _Float16* Ahs = lds;
    _Float16* Bhs = lds + 4096;

    // bijective XCD swizzle (nwg=1875): q8=234, r8=3
    const int bid = blockIdx.x;
    const int q8 = 1875 / 8, r8 = 1875 % 8;
    const int xcd = bid & 7, wi = bid >> 3;
    const int wg = (xcd < r8 ? xcd * (q8 + 1) : r8 * (q8 + 1) + (xcd - r8) * q8) + wi;
    const int bm = wg / 5, bn = wg % 5;

    const int tid = threadIdx.x;
    const int wid = tid >> 6, lane = tid & 63;
    const int fr = lane & 15, fq = lane >> 4;
    const int wm = (wid >> 1) * 64, wn = (wid & 1) * 64;

    const float*     Ag  = X  + (size_t)(bm * 128) * KDIM;
    const _Float16*  Bhg = Wh + (size_t)(bn * 128) * KDIM;

    f32x4 acc[4][4];
    #pragma unroll
    for (int i = 0; i < 4; ++i)
        #pragma unroll
        for (int j = 0; j < 4; ++j)
            acc[i][j] = (f32x4){0.f, 0.f, 0.f, 0.f};

    for (int kk = 0; kk < 16; ++kk) {
        const int kh = kk * 32;
        // B staging via GLD16 (2 per lane)
        #pragma unroll
        for (int q = 0; q < 2; ++q) {
            const int c = wid * 2 + q;
            const int srow = lane >> 2, sc8 = (lane & 3) * 8;
            const size_t go = (size_t)(c * 16 + srow) * KDIM + kh + sc8;
            GLD16(Bhg + go, Bhs + c * 512);
        }
        // A staging: f32 -> f16 hi in-register -> LDS
        #pragma unroll
        for (int c = 0; c < 2; ++c) {
            const int idx8 = c * 256 + tid;
            const int row = idx8 >> 2, k8 = (idx8 & 3) * 8;
            const float4* xp = (const float4*)(Ag + (size_t)row * KDIM + kh + k8);
            float4 v0 = xp[0], v1 = xp[1];
            float xs[8] = {v0.x, v0.y, v0.z, v0.w, v1.x, v1.y, v1.z, v1.w};
            f16x8 h;
            #pragma unroll
            for (int q = 0; q < 8; ++q) h[q] = (_Float16)xs[q];
            *(f16x8*)&Ahs[row * 32 + k8] = h;
        }
        __syncthreads();

        f16x8 ah[4], bh[4];
        #pragma unroll
        for (int i = 0; i < 4; ++i) {
            const int ro = (wm + i * 16 + fr) * 32 + fq * 8;
            ah[i] = *(const f16x8*)&Ahs[ro];
            const int co = (wn + i * 16 + fr) * 32 + fq * 8;
            bh[i] = *(const f16x8*)&Bhs[co];
        }
        #pragma unroll
        for (int i = 0; i < 4; ++i)
            #pragma unroll
            for (int j = 0; j < 4; ++j)
                acc[i][j] = __builtin_amdgcn_mfma_f32_16x16x32_f16(ah[i], bh[j], acc[i][j], 0, 0, 0);
        __syncthreads();
    }

    // C/D layout: col = lane&15, row = (lane>>4)*4 + reg   [m89-verified]
    #pragma unroll
    for (int i = 0; i < 4; ++i) {
        #pragma unroll
        for (int r = 0; r < 4; ++r) {
            const int m = bm * 128 + wm + i * 16 + fq * 4 + r;
            float* orow = Lout + (size_t)m * GE + bn * 128 + wn;
            #pragma unroll
            for (int j = 0; j < 4; ++j) {
                const int n = bn * 128 + wn + j * 16 + fr;
                orow[j * 16 + fr] = acc[i][j][r] + bvec[n];
            }
        }
    }
}

// ---------------- helpers -------------------------------------------------
__device__ __forceinline__ bool better(float a, int ia, float b, int ib) {
    return (a > b) || (a == b && ia < ib);
}

// ---------------- Kernel B: epilogue (fused single butterfly) -------------
// One 5-step butterfly carries {plain max+idx, online softmax sum, gumbel
// top-2}: 7 independent shfl per step, replacing three sequential
// butterflies. Post-butterfly softmax needs ONE exp (rescale from local
// max) instead of ten.
__global__ __launch_bounds__(256) void epilogue_kernel(
    const float* __restrict__ X, const float* __restrict__ Wf,
    const float* __restrict__ bvec,
    const float* __restrict__ entries, const float* __restrict__ gumbel,
    float* __restrict__ out, float* __restrict__ gavgp,
    unsigned int* __restrict__ gcnt)
{
    __shared__ float s_avgp[GE];
    __shared__ unsigned int s_cnt[GE];
    __shared__ unsigned int s_nflag;
    __shared__ uint2 s_flags[64];               // exact cap: 32 rows x 2 cb
    const int tid = threadIdx.x;
    for (int i = tid; i < GE; i += 256) { s_avgp[i] = 0.f; s_cnt[i] = 0u; }
    if (tid == 0) s_nflag = 0u;
    __syncthreads();

    const int wave = tid >> 6, lane = tid & 63;
    const int h = lane >> 5, il = lane & 31;

    float accp[10];
    #pragma unroll
    for (int i = 0; i < 10; ++i) accp[i] = 0.f;

    float* cb = out + CB_OFF;

    for (int rr = 0; rr < 8; ++rr) {
        const int n = blockIdx.x * 32 + wave * 8 + rr;
        float* Lrow = cb + (size_t)n * GE + h * NE;
        const float* Urow = gumbel + (size_t)(2 * n + h) * NE;

        // pure load loop: no cross-iteration deps
        float lg[10], uu[10];
        #pragma unroll
        for (int i = 0; i < 10; ++i) {
            const int e = il + 32 * i;
            lg[i] = Lrow[e];
            uu[i] = Urow[e];
        }

        // local pass: plain top-1, gumbel top-3, (no butterfly deps yet)
        float pv = lg[0]; int pi = il;
        float l1 = -3.4e38f, l2 = -3.4e38f, l3 = -3.4e38f;
        int   li1 = 0x7ffffffd, li2 = 0x7ffffffe, li3 = 0x7fffffff;
        #pragma unroll
        for (int i = 0; i < 10; ++i) {
            const int e = il + 32 * i;
            if (i > 0 && better(lg[i], e, pv, pi)) { pv = lg[i]; pi = e; }
            const float z = lg[i] - __logf(-__logf(uu[i] + 1e-10f) + 1e-10f);
            if (better(z, e, l1, li1)) { l3 = l2; li3 = li2; l2 = l1; li2 = li1; l1 = z; li1 = e; }
            else if (better(z, e, l2, li2)) { l3 = l2; li3 = li2; l2 = z; li2 = e; }
            else if (better(z, e, l3, li3)) { l3 = z; li3 = e; }
        }
        // local softmax partials against LOCAL max (off the butterfly chain)
        float s = 0.f, ex[10];
        #pragma unroll
        for (int i = 0; i < 10; ++i) { ex[i] = __expf(lg[i] - pv); s += ex[i]; }
        const float pvloc = pv;

        // fused butterfly: {pv,pi,s (online softmax), g1,j1,g2,j2}
        float g1 = l1, g2 = l2; int j1 = li1, j2 = li2;
        #pragma unroll
        for (int m = 1; m <= 16; m <<= 1) {
            const float opv = __shfl_xor(pv, m);
            const int   opi = __shfl_xor(pi, m);
            const float os  = __shfl_xor(s, m);
            const float o1 = __shfl_xor(g1, m); const int q1 = __shfl_xor(j1, m);
            const float o2 = __shfl_xor(g2, m); const int q2 = __shfl_xor(j2, m);
            // plain max + online-softmax-sum merge
            if (better(opv, opi, pv, pi)) {
                s = s * __expf(pv - opv) + os;
                pv = opv; pi = opi;
            } else {
                s = s + os * __expf(opv - pv);
            }
            // gumbel top-2 merge
            if (better(o1, q1, g1, j1)) {
                const float tv = g1; const int ti = j1;
                g1 = o1; j1 = q1;
                if (better(o2, q2, tv, ti)) { g2 = o2; j2 = q2; }
                else                        { g2 = tv; j2 = ti; }
            } else if (better(o1, q1, g2, j2)) {
                g2 = o1; j2 = q1;
            }
        }

        // rare near-tie: extract global 3rd, flag into block-local LDS list
        if (g1 - g2 < MARGIN) {
            float c; int ci;
            if (li1 != j1 && li1 != j2)      { c = l1; ci = li1; }
            else if (li2 != j1 && li2 != j2) { c = l2; ci = li2; }
            else                             { c = l3; ci = li3; }
            #pragma unroll
            for (int m = 1; m <= 16; m <<= 1) {
                const float oc = __shfl_xor(c, m);
                const int   oi = __shfl_xor(ci, m);
                if (better(oc, oi, c, ci)) { c = oc; ci = oi; }
            }
            if (il == 0) {
                unsigned ix = atomicAdd(&s_nflag, 1u);
                if (ix < 64u)
                    s_flags[ix] = make_uint2((unsigned)n | ((unsigned)h << 16),
                                             (unsigned)j1 | ((unsigned)j2 << 9) |
                                             ((unsigned)ci << 18));
            }
        }

        // softmax accumulation: single rescale exp instead of ten
        const float scale = __expf(pvloc - pv) / s;
        #pragma unroll
        for (int i = 0; i < 10; ++i) accp[i] += ex[i] * scale;

        if (il == 0) atomicAdd(&s_cnt[h * NE + pi], 1u);

        // one-hot cb write (overwrites consumed logits row)
        #pragma unroll
        for (int i = 0; i < 10; ++i) {
            const int e = il + 32 * i;
            Lrow[e] = (e == j1) ? 1.f : 0.f;
        }
        // quantized gather
        const float* ent = entries + (size_t)(h * NE + j1) * DDIM;
        float* qrow = out + (size_t)n * ODIM + h * DDIM;
        #pragma unroll
        for (int j = 0; j < 12; ++j) {
            const int d = il + 32 * j;
            qrow[d] = ent[d];
        }
    }

    #pragma unroll
    for (int i = 0; i < 10; ++i)
        atomicAdd(&s_avgp[h * NE + il + 32 * i], accp[i]);
    __syncthreads();                 // drains hot-loop stores + flag list
    for (int i = tid; i < GE; i += 256) {
        atomicAdd(&gavgp[i], s_avgp[i]);
        unsigned int c = s_cnt[i];
        if (c) atomicAdd(&gcnt[i], c);
    }

    // ---- cold path: fp64 re-resolve of this block's flagged near-ties ----
    unsigned nf = s_nflag; if (nf > 64u) nf = 64u;
    for (unsigned f = wave; f < nf; f += 4) {
        const uint2 fl = s_flags[f];
        const int n  = fl.x & 0xffff;
        const int hh = (fl.x >> 16) & 1;
        const int c1 = fl.y & 511, c2 = (fl.y >> 9) & 511, c3 = (fl.y >> 18) & 511;

        const float* xr = X + (size_t)n * KDIM;
        const float* w1 = Wf + (size_t)(hh * NE + c1) * KDIM;
        const float* w2 = Wf + (size_t)(hh * NE + c2) * KDIM;
        const float* w3 = Wf + (size_t)(hh * NE + c3) * KDIM;
        double d1 = 0.0, d2 = 0.0, d3 = 0.0;
        #pragma unroll
        for (int j = 0; j < 8; ++j) {
            const int k = lane + 64 * j;
            const double xv = (double)xr[k];
            d1 += xv * (double)w1[k];
            d2 += xv * (double)w2[k];
            d3 += xv * (double)w3[k];
        }
        #pragma unroll
        for (int m = 1; m <= 32; m <<= 1) {
            d1 += __shfl_xor(d1, m);
            d2 += __shfl_xor(d2, m);
            d3 += __shfl_xor(d3, m);
        }
        const float* Ur = gumbel + (size_t)(2 * n + hh) * NE;
        d1 += (double)bvec[hh * NE + c1] - log(-log((double)Ur[c1] + 1e-10) + 1e-10);
        d2 += (double)bvec[hh * NE + c2] - log(-log((double)Ur[c2] + 1e-10) + 1e-10);
        d3 += (double)bvec[hh * NE + c3] - log(-log((double)Ur[c3] + 1e-10) + 1e-10);

        int kb = c1; double db = d1;
        if (d2 > db || (d2 == db && c2 < kb)) { kb = c2; db = d2; }
        if (d3 > db || (d3 == db && c3 < kb)) { kb = c3; db = d3; }

        if (kb != c1) {
            float* Lrow = cb + (size_t)n * GE + hh * NE;
            if (lane == 0) { Lrow[c1] = 0.f; Lrow[kb] = 1.f; }
            const float* ent = entries + (size_t)(hh * NE + kb) * DDIM;
            float* qrow = out + (size_t)n * ODIM + hh * DDIM;
            #pragma unroll
            for (int t = 0; t < 6; ++t) {
                const int d = lane + 64 * t;
                qrow[d] = ent[d];
            }
        }
    }
}

// ---------------- Kernel C: perplexity scalars ----------------------------
__global__ void finalize_kernel(const float* __restrict__ gavgp,
                                const unsigned int* __restrict__ gcnt,
                                float* __restrict__ out)
{
    __shared__ double sc[GE], sp[GE];
    const int t = threadIdx.x;
    if (t < GE) {
        double hp = (double)gcnt[t] * (1.0 / 48000.0);
        sc[t] = hp * log(hp + 1e-7);
        double ap = (double)gavgp[t] * (1.0 / 48000.0);
        sp[t] = ap * log(ap + 1e-7);
    }
    __syncthreads();
    if (t == 0) {
        double c0 = 0, c1 = 0, p0 = 0, p1 = 0;
        for (int e = 0; e < NE; ++e) { c0 += sc[e]; p0 += sp[e]; }
        for (int e = NE; e < GE; ++e) { c1 += sc[e]; p1 += sp[e]; }
        out[SC_OFF]     = (float)(exp(-c0) + exp(-c1));
        out[SC_OFF + 1] = (float)(exp(-p0) + exp(-p1));
    }
}

// ---------------- launch --------------------------------------------------
extern "C" void kernel_launch(void* const* d_in, const int* in_sizes, int n_in,
                              void* d_out, int out_size, void* d_ws, size_t ws_size,
                              hipStream_t stream)
{
    const float* X       = (const float*)d_in[0];
    const float* Wf      = (const float*)d_in[1];
    const float* bvec    = (const float*)d_in[2];
    const float* entries = (const float*)d_in[3];
    const float* gumbel  = (const float*)d_in[4];
    float* out = (float*)d_out;

    float* gavgp = (float*)d_ws;                                    // 2560 B
    unsigned int* gcnt = (unsigned int*)((char*)d_ws + 2560);       // 2560 B
    _Float16* Wh = (_Float16*)((char*)d_ws + 8192);                 // 640 KB

    hipMemsetAsync(d_ws, 0, 8192, stream);
    split_hi<<<160, 256, 0, stream>>>(Wf, Wh, 40960);               // 640*512/8
    gemm_cvt<<<1875, 256, 0, stream>>>(X, Wh, bvec, out + CB_OFF);
    epilogue_kernel<<<1500, 256, 0, stream>>>(X, Wf, bvec, entries, gumbel,
                                              out, gavgp, gcnt);
    finalize_kernel<<<1, 640, 0, stream>>>(gavgp, gcnt, out);
}